// Round 1
// baseline (294.934 us; speedup 1.0000x reference)
//
#include <hip/hip_runtime.h>

#define N_VERT 50000
#define KNBR 20
#define F 128
#define M_TILE 16

// ---------------------------------------------------------------------------
// Kernel A: three projections  Zc = V@Wc, Pint = V@Wi, Pnh = V@Wn
// Block = 128 threads (one per filter f), M_TILE=16 vertex rows per block.
// Vertex rows staged in LDS (reads are wave-broadcast: same addr all lanes).
// W column reads are coalesced across f and L2-resident (3 x 64 KB).
// ---------------------------------------------------------------------------
__global__ __launch_bounds__(128) void proj_kernel(
    const float* __restrict__ vert,
    const float* __restrict__ Wc,
    const float* __restrict__ Wi,
    const float* __restrict__ Wn,
    float* __restrict__ zc,
    float* __restrict__ pi,
    float* __restrict__ pn)
{
    __shared__ float rows[M_TILE][F];
    const int f  = threadIdx.x;
    const int i0 = blockIdx.x * M_TILE;

#pragma unroll
    for (int m = 0; m < M_TILE; ++m)
        rows[m][f] = vert[(size_t)(i0 + m) * F + f];
    __syncthreads();

    float ac[M_TILE], ai[M_TILE], an[M_TILE];
#pragma unroll
    for (int m = 0; m < M_TILE; ++m) { ac[m] = 0.f; ai[m] = 0.f; an[m] = 0.f; }

#pragma unroll 4
    for (int k = 0; k < F; ++k) {
        float wc = Wc[k * F + f];
        float wi = Wi[k * F + f];
        float wn = Wn[k * F + f];
#pragma unroll
        for (int m = 0; m < M_TILE; ++m) {
            float v = rows[m][k];
            ac[m] = fmaf(v, wc, ac[m]);
            ai[m] = fmaf(v, wi, ai[m]);
            an[m] = fmaf(v, wn, an[m]);
        }
    }

#pragma unroll
    for (int m = 0; m < M_TILE; ++m) {
        size_t o = (size_t)(i0 + m) * F + f;
        zc[o] = ac[m];
        pi[o] = ai[m];
        pn[o] = an[m];
    }
}

// ---------------------------------------------------------------------------
// Kernel B: gather-aggregate both edge types + bias + relu.
// One block (128 threads) per vertex. idx/edge loads are block-uniform
// (scalar path, uniform branch -> no divergence); gathered rows coalesce
// across the 128 lanes (512 B per row).
// ---------------------------------------------------------------------------
__global__ __launch_bounds__(128) void agg_kernel(
    const float* __restrict__ pi,
    const float* __restrict__ pn,
    const int*   __restrict__ int_idx,
    const int*   __restrict__ nh_idx,
    const float* __restrict__ int_e,
    const float* __restrict__ nh_e,
    const float* __restrict__ bv,
    float* __restrict__ z)   // holds Zc on entry; overwritten with result
{
    const int i = blockIdx.x;
    const int f = threadIdx.x;

    float acc_i = 0.f, acc_n = 0.f;
    int ci = 0, cn = 0;

#pragma unroll
    for (int k = 0; k < KNBR; ++k) {
        int   idx = int_idx[i * KNBR + k];
        float e   = int_e[i * KNBR + k];
        if (idx >= 0) { ++ci; acc_i = fmaf(pi[(size_t)idx * F + f], e, acc_i); }
    }
#pragma unroll
    for (int k = 0; k < KNBR; ++k) {
        int   idx = nh_idx[i * KNBR + k];
        float e   = nh_e[i * KNBR + k];
        if (idx >= 0) { ++cn; acc_n = fmaf(pn[(size_t)idx * F + f], e, acc_n); }
    }

    size_t o = (size_t)i * F + f;
    float r = z[o] + acc_i / (float)max(ci, 1) + acc_n / (float)max(cn, 1) + bv[f];
    z[o] = fmaxf(r, 0.f);
}

// ---------------------------------------------------------------------------
// Kernel C: passthrough outputs 1..5, written as float32 VALUES
// (harness reads the whole flat output as float32).
// ---------------------------------------------------------------------------
__global__ void pass_kernel(const int*   __restrict__ nh_idx,
                            const int*   __restrict__ int_idx,
                            const float* __restrict__ nh_e,
                            const float* __restrict__ int_e,
                            const int*   __restrict__ is_int,
                            float* __restrict__ out)
{
    const size_t NK    = (size_t)N_VERT * KNBR;
    const size_t total = 4 * NK + N_VERT;
    size_t t = (size_t)blockIdx.x * blockDim.x + threadIdx.x;
    if (t >= total) return;

    float v;
    if      (t <     NK) v = (float)nh_idx[t];
    else if (t < 2 * NK) v = (float)int_idx[t - NK];
    else if (t < 3 * NK) v = nh_e[t - 2 * NK];
    else if (t < 4 * NK) v = int_e[t - 3 * NK];
    else                 v = (float)is_int[t - 4 * NK];
    out[t] = v;
}

extern "C" void kernel_launch(void* const* d_in, const int* in_sizes, int n_in,
                              void* d_out, int out_size, void* d_ws, size_t ws_size,
                              hipStream_t stream) {
    const float* vert    = (const float*)d_in[0];
    const int*   nh_idx  = (const int*)  d_in[1];
    const int*   int_idx = (const int*)  d_in[2];
    const float* nh_e    = (const float*)d_in[3];
    const float* int_e   = (const float*)d_in[4];
    const int*   is_int  = (const int*)  d_in[5];
    const float* Wc      = (const float*)d_in[6];
    const float* Wi      = (const float*)d_in[7];
    const float* Wn      = (const float*)d_in[8];
    const float* bv      = (const float*)d_in[9];

    float* z        = (float*)d_out;                 // [N, F]
    float* out_rest = z + (size_t)N_VERT * F;        // passthrough chunks
    float* pi       = (float*)d_ws;                  // [N, F]
    float* pn       = pi + (size_t)N_VERT * F;       // [N, F]

    proj_kernel<<<N_VERT / M_TILE, 128, 0, stream>>>(vert, Wc, Wi, Wn, z, pi, pn);
    agg_kernel<<<N_VERT, 128, 0, stream>>>(pi, pn, int_idx, nh_idx, int_e, nh_e, bv, z);

    const size_t total = (size_t)4 * N_VERT * KNBR + N_VERT;
    pass_kernel<<<(int)((total + 255) / 256), 256, 0, stream>>>(
        nh_idx, int_idx, nh_e, int_e, is_int, out_rest);
}

// Round 2
// 250.861 us; speedup vs baseline: 1.1757x; 1.1757x over previous
//
#include <hip/hip_runtime.h>

#define N_VERT 50000
#define KNBR 20
#define F 128
#define M_TILE 16

typedef unsigned int uint32;
typedef unsigned short ushort16;

// ---------------------------------------------------------------------------
// Kernel A: three projections. Zc (f32, to d_out) and Pint/Pnh (bf16, to ws).
// Block = 128 threads (one per filter f), M_TILE=16 vertex rows per block.
// ---------------------------------------------------------------------------
__global__ __launch_bounds__(128) void proj_kernel(
    const float* __restrict__ vert,
    const float* __restrict__ Wc,
    const float* __restrict__ Wi,
    const float* __restrict__ Wn,
    float*    __restrict__ zc,
    ushort16* __restrict__ pi,   // bf16 [N, F]
    ushort16* __restrict__ pn)   // bf16 [N, F]
{
    __shared__ float rows[M_TILE][F];
    const int f  = threadIdx.x;
    const int i0 = blockIdx.x * M_TILE;

#pragma unroll
    for (int m = 0; m < M_TILE; ++m)
        rows[m][f] = vert[(size_t)(i0 + m) * F + f];
    __syncthreads();

    float ac[M_TILE], ai[M_TILE], an[M_TILE];
#pragma unroll
    for (int m = 0; m < M_TILE; ++m) { ac[m] = 0.f; ai[m] = 0.f; an[m] = 0.f; }

#pragma unroll 4
    for (int k = 0; k < F; ++k) {
        float wc = Wc[k * F + f];
        float wi = Wi[k * F + f];
        float wn = Wn[k * F + f];
#pragma unroll
        for (int m = 0; m < M_TILE; ++m) {
            float v = rows[m][k];
            ac[m] = fmaf(v, wc, ac[m]);
            ai[m] = fmaf(v, wi, ai[m]);
            an[m] = fmaf(v, wn, an[m]);
        }
    }

#pragma unroll
    for (int m = 0; m < M_TILE; ++m) {
        size_t o = (size_t)(i0 + m) * F + f;
        zc[o] = ac[m];
        // f32 -> bf16 round-to-nearest-even
        uint32 bi = __float_as_uint(ai[m]);
        bi += 0x7fff + ((bi >> 16) & 1);
        pi[o] = (ushort16)(bi >> 16);
        uint32 bn = __float_as_uint(an[m]);
        bn += 0x7fff + ((bn >> 16) & 1);
        pn[o] = (ushort16)(bn >> 16);
    }
}

// ---------------------------------------------------------------------------
// Kernel B: gather-aggregate (bf16 payload) + bias + relu.
// One WAVE per vertex (block = 256 = 4 waves). Lane l handles filters
// 2l, 2l+1 via a single dword gather -> 256 B per row per gather.
// idx/edge loads are wave-uniform (broadcast); the pad branch is uniform.
// ---------------------------------------------------------------------------
__global__ __launch_bounds__(256) void agg_kernel(
    const uint32* __restrict__ pi,   // bf16x2 [N, 64]
    const uint32* __restrict__ pn,   // bf16x2 [N, 64]
    const int*    __restrict__ int_idx,
    const int*    __restrict__ nh_idx,
    const float*  __restrict__ int_e,
    const float*  __restrict__ nh_e,
    const float*  __restrict__ bv,
    float* __restrict__ z)   // holds Zc on entry; overwritten with result
{
    const int wave = threadIdx.x >> 6;
    const int lane = threadIdx.x & 63;
    const int i    = blockIdx.x * 4 + wave;   // 12500 * 4 == N_VERT exactly

    float a_i0 = 0.f, a_i1 = 0.f, a_n0 = 0.f, a_n1 = 0.f;
    int ci = 0, cn = 0;

#pragma unroll
    for (int k = 0; k < KNBR; ++k) {
        int   idx = int_idx[i * KNBR + k];
        float e   = int_e[i * KNBR + k];
        if (idx >= 0) {
            ++ci;
            uint32 p = pi[(size_t)idx * 64 + lane];
            a_i0 = fmaf(__uint_as_float(p << 16), e, a_i0);
            a_i1 = fmaf(__uint_as_float(p & 0xffff0000u), e, a_i1);
        }
    }
#pragma unroll
    for (int k = 0; k < KNBR; ++k) {
        int   idx = nh_idx[i * KNBR + k];
        float e   = nh_e[i * KNBR + k];
        if (idx >= 0) {
            ++cn;
            uint32 p = pn[(size_t)idx * 64 + lane];
            a_n0 = fmaf(__uint_as_float(p << 16), e, a_n0);
            a_n1 = fmaf(__uint_as_float(p & 0xffff0000u), e, a_n1);
        }
    }

    float ri = 1.f / (float)max(ci, 1);
    float rn = 1.f / (float)max(cn, 1);

    size_t o = (size_t)i * F + 2 * lane;
    float2 zc = *(const float2*)&z[o];
    float r0 = zc.x + a_i0 * ri + a_n0 * rn + bv[2 * lane];
    float r1 = zc.y + a_i1 * ri + a_n1 * rn + bv[2 * lane + 1];
    float2 res = make_float2(fmaxf(r0, 0.f), fmaxf(r1, 0.f));
    *(float2*)&z[o] = res;
}

// ---------------------------------------------------------------------------
// Kernel C: passthrough outputs 1..5, written as float32 VALUES.
// ---------------------------------------------------------------------------
__global__ void pass_kernel(const int*   __restrict__ nh_idx,
                            const int*   __restrict__ int_idx,
                            const float* __restrict__ nh_e,
                            const float* __restrict__ int_e,
                            const int*   __restrict__ is_int,
                            float* __restrict__ out)
{
    const size_t NK    = (size_t)N_VERT * KNBR;
    const size_t total = 4 * NK + N_VERT;
    size_t t = (size_t)blockIdx.x * blockDim.x + threadIdx.x;
    if (t >= total) return;

    float v;
    if      (t <     NK) v = (float)nh_idx[t];
    else if (t < 2 * NK) v = (float)int_idx[t - NK];
    else if (t < 3 * NK) v = nh_e[t - 2 * NK];
    else if (t < 4 * NK) v = int_e[t - 3 * NK];
    else                 v = (float)is_int[t - 4 * NK];
    out[t] = v;
}

extern "C" void kernel_launch(void* const* d_in, const int* in_sizes, int n_in,
                              void* d_out, int out_size, void* d_ws, size_t ws_size,
                              hipStream_t stream) {
    const float* vert    = (const float*)d_in[0];
    const int*   nh_idx  = (const int*)  d_in[1];
    const int*   int_idx = (const int*)  d_in[2];
    const float* nh_e    = (const float*)d_in[3];
    const float* int_e   = (const float*)d_in[4];
    const int*   is_int  = (const int*)  d_in[5];
    const float* Wc      = (const float*)d_in[6];
    const float* Wi      = (const float*)d_in[7];
    const float* Wn      = (const float*)d_in[8];
    const float* bv      = (const float*)d_in[9];

    float* z        = (float*)d_out;                 // [N, F]
    float* out_rest = z + (size_t)N_VERT * F;        // passthrough chunks
    ushort16* pi    = (ushort16*)d_ws;               // bf16 [N, F]
    ushort16* pn    = pi + (size_t)N_VERT * F;       // bf16 [N, F]

    proj_kernel<<<N_VERT / M_TILE, 128, 0, stream>>>(vert, Wc, Wi, Wn, z, pi, pn);
    agg_kernel<<<N_VERT / 4, 256, 0, stream>>>(
        (const uint32*)pi, (const uint32*)pn, int_idx, nh_idx, int_e, nh_e, bv, z);

    const size_t total = (size_t)4 * N_VERT * KNBR + N_VERT;
    pass_kernel<<<(int)((total + 255) / 256), 256, 0, stream>>>(
        nh_idx, int_idx, nh_e, int_e, is_int, out_rest);
}

// Round 3
// 165.555 us; speedup vs baseline: 1.7815x; 1.5153x over previous
//
#include <hip/hip_runtime.h>

#define N_VERT 50000
#define KNBR 20
#define F 128
#define M_TILE 16

typedef unsigned int uint32;
typedef unsigned short ushort16;

// ---------------------------------------------------------------------------
// Kernel A: three projections. Zc (f32, to d_out) and Pint/Pnh (bf16, to ws).
// Block = 128 threads (one per filter f), M_TILE=16 vertex rows per block.
// ---------------------------------------------------------------------------
__global__ __launch_bounds__(128) void proj_kernel(
    const float* __restrict__ vert,
    const float* __restrict__ Wc,
    const float* __restrict__ Wi,
    const float* __restrict__ Wn,
    float*    __restrict__ zc,
    ushort16* __restrict__ pi,   // bf16 [N, F]
    ushort16* __restrict__ pn)   // bf16 [N, F]
{
    __shared__ float rows[M_TILE][F];
    const int f  = threadIdx.x;
    const int i0 = blockIdx.x * M_TILE;

#pragma unroll
    for (int m = 0; m < M_TILE; ++m)
        rows[m][f] = vert[(size_t)(i0 + m) * F + f];
    __syncthreads();

    float ac[M_TILE], ai[M_TILE], an[M_TILE];
#pragma unroll
    for (int m = 0; m < M_TILE; ++m) { ac[m] = 0.f; ai[m] = 0.f; an[m] = 0.f; }

#pragma unroll 4
    for (int k = 0; k < F; ++k) {
        float wc = Wc[k * F + f];
        float wi = Wi[k * F + f];
        float wn = Wn[k * F + f];
#pragma unroll
        for (int m = 0; m < M_TILE; ++m) {
            float v = rows[m][k];
            ac[m] = fmaf(v, wc, ac[m]);
            ai[m] = fmaf(v, wi, ai[m]);
            an[m] = fmaf(v, wn, an[m]);
        }
    }

#pragma unroll
    for (int m = 0; m < M_TILE; ++m) {
        size_t o = (size_t)(i0 + m) * F + f;
        zc[o] = ac[m];
        uint32 bi = __float_as_uint(ai[m]);
        bi += 0x7fff + ((bi >> 16) & 1);
        pi[o] = (ushort16)(bi >> 16);
        uint32 bn = __float_as_uint(an[m]);
        bn += 0x7fff + ((bn >> 16) & 1);
        pn[o] = (ushort16)(bn >> 16);
    }
}

// ---------------------------------------------------------------------------
// Kernel B: gather-aggregate (bf16 payload) + bias + relu.
// One WAVE per vertex; lane handles filters 2l, 2l+1 (one dword per gather).
// ALL gathers unconditional (safe index max(idx,0), validity folded into a
// masked edge weight) so the fully-unrolled loop issues 40 independent
// gathers back-to-back -> MLP ~40 per wave instead of branch-serialized.
// idx/edge preloads vectorized as int4/float4 (80 B/vertex is 16B-aligned).
// ---------------------------------------------------------------------------
__global__ __launch_bounds__(256) void agg_kernel(
    const uint32* __restrict__ pi,   // bf16x2 [N, 64]
    const uint32* __restrict__ pn,   // bf16x2 [N, 64]
    const int4*   __restrict__ int_idx4,
    const int4*   __restrict__ nh_idx4,
    const float4* __restrict__ int_e4,
    const float4* __restrict__ nh_e4,
    const float*  __restrict__ bv,
    float* __restrict__ z)   // holds Zc on entry; overwritten with result
{
    const int wave = threadIdx.x >> 6;
    const int lane = threadIdx.x & 63;
    const int i    = blockIdx.x * 4 + wave;   // 12500 * 4 == N_VERT exactly

    int   si[KNBR], sn[KNBR];   // safe (clamped) indices
    float ie[KNBR], ne[KNBR];   // masked edge weights
    int ci = 0, cn = 0;

#pragma unroll
    for (int q = 0; q < KNBR / 4; ++q) {
        int4   a = int_idx4[i * 5 + q];
        int4   b = nh_idx4[i * 5 + q];
        float4 c = int_e4[i * 5 + q];
        float4 d = nh_e4[i * 5 + q];
        int av[4] = {a.x, a.y, a.z, a.w};
        int bvv[4] = {b.x, b.y, b.z, b.w};
        float cv[4] = {c.x, c.y, c.z, c.w};
        float dv[4] = {d.x, d.y, d.z, d.w};
#pragma unroll
        for (int j = 0; j < 4; ++j) {
            int k = 4 * q + j;
            bool vi = av[j] >= 0;
            bool vn = bvv[j] >= 0;
            ci += vi; cn += vn;
            si[k] = vi ? av[j] : 0;
            sn[k] = vn ? bvv[j] : 0;
            ie[k] = vi ? cv[j] : 0.f;
            ne[k] = vn ? dv[j] : 0.f;
        }
    }

    // issue all 40 gathers unconditionally
    uint32 gi[KNBR], gn[KNBR];
#pragma unroll
    for (int k = 0; k < KNBR; ++k) {
        gi[k] = pi[(size_t)si[k] * 64 + lane];
        gn[k] = pn[(size_t)sn[k] * 64 + lane];
    }

    float a_i0 = 0.f, a_i1 = 0.f, a_n0 = 0.f, a_n1 = 0.f;
#pragma unroll
    for (int k = 0; k < KNBR; ++k) {
        a_i0 = fmaf(__uint_as_float(gi[k] << 16),        ie[k], a_i0);
        a_i1 = fmaf(__uint_as_float(gi[k] & 0xffff0000u), ie[k], a_i1);
        a_n0 = fmaf(__uint_as_float(gn[k] << 16),        ne[k], a_n0);
        a_n1 = fmaf(__uint_as_float(gn[k] & 0xffff0000u), ne[k], a_n1);
    }

    float ri = 1.f / (float)max(ci, 1);
    float rn = 1.f / (float)max(cn, 1);

    size_t o = (size_t)i * F + 2 * lane;
    float2 zc = *(const float2*)&z[o];
    float r0 = zc.x + a_i0 * ri + a_n0 * rn + bv[2 * lane];
    float r1 = zc.y + a_i1 * ri + a_n1 * rn + bv[2 * lane + 1];
    *(float2*)&z[o] = make_float2(fmaxf(r0, 0.f), fmaxf(r1, 0.f));
}

// ---------------------------------------------------------------------------
// Kernel C: passthrough outputs 1..5, written as float32 VALUES.
// ---------------------------------------------------------------------------
__global__ void pass_kernel(const int*   __restrict__ nh_idx,
                            const int*   __restrict__ int_idx,
                            const float* __restrict__ nh_e,
                            const float* __restrict__ int_e,
                            const int*   __restrict__ is_int,
                            float* __restrict__ out)
{
    const size_t NK    = (size_t)N_VERT * KNBR;
    const size_t total = 4 * NK + N_VERT;
    size_t t = (size_t)blockIdx.x * blockDim.x + threadIdx.x;
    if (t >= total) return;

    float v;
    if      (t <     NK) v = (float)nh_idx[t];
    else if (t < 2 * NK) v = (float)int_idx[t - NK];
    else if (t < 3 * NK) v = nh_e[t - 2 * NK];
    else if (t < 4 * NK) v = int_e[t - 3 * NK];
    else                 v = (float)is_int[t - 4 * NK];
    out[t] = v;
}

extern "C" void kernel_launch(void* const* d_in, const int* in_sizes, int n_in,
                              void* d_out, int out_size, void* d_ws, size_t ws_size,
                              hipStream_t stream) {
    const float* vert    = (const float*)d_in[0];
    const int*   nh_idx  = (const int*)  d_in[1];
    const int*   int_idx = (const int*)  d_in[2];
    const float* nh_e    = (const float*)d_in[3];
    const float* int_e   = (const float*)d_in[4];
    const int*   is_int  = (const int*)  d_in[5];
    const float* Wc      = (const float*)d_in[6];
    const float* Wi      = (const float*)d_in[7];
    const float* Wn      = (const float*)d_in[8];
    const float* bv      = (const float*)d_in[9];

    float* z        = (float*)d_out;                 // [N, F]
    float* out_rest = z + (size_t)N_VERT * F;        // passthrough chunks
    ushort16* pi    = (ushort16*)d_ws;               // bf16 [N, F]
    ushort16* pn    = pi + (size_t)N_VERT * F;       // bf16 [N, F]

    proj_kernel<<<N_VERT / M_TILE, 128, 0, stream>>>(vert, Wc, Wi, Wn, z, pi, pn);
    agg_kernel<<<N_VERT / 4, 256, 0, stream>>>(
        (const uint32*)pi, (const uint32*)pn,
        (const int4*)int_idx, (const int4*)nh_idx,
        (const float4*)int_e, (const float4*)nh_e, bv, z);

    const size_t total = (size_t)4 * N_VERT * KNBR + N_VERT;
    pass_kernel<<<(int)((total + 255) / 256), 256, 0, stream>>>(
        nh_idx, int_idx, nh_e, int_e, is_int, out_rest);
}

// Round 4
// 150.094 us; speedup vs baseline: 1.9650x; 1.1030x over previous
//
#include <hip/hip_runtime.h>

#define N_VERT 50000
#define KNBR 20
#define F 128

typedef unsigned int uint32;
typedef unsigned short ushort16;
typedef __attribute__((ext_vector_type(8))) short bf16x8;
typedef __attribute__((ext_vector_type(4))) float f32x4;

__device__ __forceinline__ ushort16 f2bf(float x) {
    uint32 u = __float_as_uint(x);
    u += 0x7fff + ((u >> 16) & 1);        // round-to-nearest-even
    return (ushort16)(u >> 16);
}

// ---------------------------------------------------------------------------
// Kernel W: transpose+convert the three 128x128 weights to bf16, n-major:
// Wt[w][n][k] = bf16(W_w[k][n]).  192 KB total, L2-resident for the GEMM.
// ---------------------------------------------------------------------------
__global__ __launch_bounds__(256) void wconv_kernel(
    const float* __restrict__ Wc, const float* __restrict__ Wi,
    const float* __restrict__ Wn, ushort16* __restrict__ Wt)
{
    int t = blockIdx.x * 256 + threadIdx.x;
    if (t >= 3 * F * F) return;
    int w = t >> 14;          // matrix id
    int r = t & 16383;
    int n = r & 127;          // fastest -> coalesced source read
    int k = r >> 7;
    const float* W = (w == 0) ? Wc : ((w == 1) ? Wi : Wn);
    Wt[w * F * F + n * F + k] = f2bf(W[k * F + n]);
}

// ---------------------------------------------------------------------------
// Kernel A: three projections via bf16 MFMA (16x16x32).
// Block = 256 (4 waves), 64 rows/block; each wave: 16 rows x 128 cols x 3 W's
// = 96 MFMAs. A-fragments: V rows read f32 once, converted inline.
// B-fragments: contiguous 16B loads from Wt (L2-resident).
// Layouts (m89-verified): A row=lane&15, k=(lane>>4)*8+j;
//                         B col=lane&15, k=(lane>>4)*8+j;
//                         D col=lane&15, row=(lane>>4)*4+j.
// ---------------------------------------------------------------------------
__global__ __launch_bounds__(256) void mfma_proj_kernel(
    const float*    __restrict__ vert,
    const ushort16* __restrict__ Wt,     // [3][128][128] bf16 (n-major)
    float*    __restrict__ zc,
    ushort16* __restrict__ pi,
    ushort16* __restrict__ pn)
{
    const int wave = threadIdx.x >> 6;
    const int lane = threadIdx.x & 63;
    const int lr   = lane & 15;
    const int lk   = lane >> 4;
    const int r0   = blockIdx.x * 64 + wave * 16;

    // A fragments for all 4 K-steps (V element read exactly once)
    int rowA = r0 + lr; if (rowA > N_VERT - 1) rowA = N_VERT - 1;
    const float* vrow = vert + (size_t)rowA * F;
    bf16x8 afrag[4];
#pragma unroll
    for (int kk = 0; kk < 4; ++kk) {
        const float* p = vrow + kk * 32 + lk * 8;
        f32x4 lo = *(const f32x4*)p;
        f32x4 hi = *(const f32x4*)(p + 4);
#pragma unroll
        for (int j = 0; j < 4; ++j) {
            afrag[kk][j]     = (short)f2bf(lo[j]);
            afrag[kk][4 + j] = (short)f2bf(hi[j]);
        }
    }

    f32x4 acc[3][8];
#pragma unroll
    for (int w = 0; w < 3; ++w)
#pragma unroll
        for (int nt = 0; nt < 8; ++nt) acc[w][nt] = (f32x4)(0.f);

#pragma unroll
    for (int kk = 0; kk < 4; ++kk) {
#pragma unroll
        for (int nt = 0; nt < 8; ++nt) {
            size_t boff = (size_t)(nt * 16 + lr) * F + kk * 32 + lk * 8;
#pragma unroll
            for (int w = 0; w < 3; ++w) {
                bf16x8 b = *(const bf16x8*)(Wt + w * F * F + boff);
                acc[w][nt] = __builtin_amdgcn_mfma_f32_16x16x32_bf16(
                    afrag[kk], b, acc[w][nt], 0, 0, 0);
            }
        }
    }

    // Stores: D col = nt*16+lr, row = r0 + lk*4 + j (predicated for tail block)
#pragma unroll
    for (int nt = 0; nt < 8; ++nt) {
#pragma unroll
        for (int j = 0; j < 4; ++j) {
            int row = r0 + lk * 4 + j;
            if (row < N_VERT) {
                size_t o = (size_t)row * F + nt * 16 + lr;
                zc[o] = acc[0][nt][j];
                pi[o] = f2bf(acc[1][nt][j]);
                pn[o] = f2bf(acc[2][nt][j]);
            }
        }
    }
}

// ---------------------------------------------------------------------------
// Kernel B: gather-aggregate (bf16 payload) + bias + relu.  (unchanged R3)
// ---------------------------------------------------------------------------
__global__ __launch_bounds__(256) void agg_kernel(
    const uint32* __restrict__ pi,
    const uint32* __restrict__ pn,
    const int4*   __restrict__ int_idx4,
    const int4*   __restrict__ nh_idx4,
    const float4* __restrict__ int_e4,
    const float4* __restrict__ nh_e4,
    const float*  __restrict__ bv,
    float* __restrict__ z)
{
    const int wave = threadIdx.x >> 6;
    const int lane = threadIdx.x & 63;
    const int i    = blockIdx.x * 4 + wave;

    int   si[KNBR], sn[KNBR];
    float ie[KNBR], ne[KNBR];
    int ci = 0, cn = 0;

#pragma unroll
    for (int q = 0; q < KNBR / 4; ++q) {
        int4   a = int_idx4[i * 5 + q];
        int4   b = nh_idx4[i * 5 + q];
        float4 c = int_e4[i * 5 + q];
        float4 d = nh_e4[i * 5 + q];
        int av[4] = {a.x, a.y, a.z, a.w};
        int bw[4] = {b.x, b.y, b.z, b.w};
        float cv[4] = {c.x, c.y, c.z, c.w};
        float dv[4] = {d.x, d.y, d.z, d.w};
#pragma unroll
        for (int j = 0; j < 4; ++j) {
            int k = 4 * q + j;
            bool vi = av[j] >= 0;
            bool vn = bw[j] >= 0;
            ci += vi; cn += vn;
            si[k] = vi ? av[j] : 0;
            sn[k] = vn ? bw[j] : 0;
            ie[k] = vi ? cv[j] : 0.f;
            ne[k] = vn ? dv[j] : 0.f;
        }
    }

    uint32 gi[KNBR], gn[KNBR];
#pragma unroll
    for (int k = 0; k < KNBR; ++k) {
        gi[k] = pi[(size_t)si[k] * 64 + lane];
        gn[k] = pn[(size_t)sn[k] * 64 + lane];
    }

    float a_i0 = 0.f, a_i1 = 0.f, a_n0 = 0.f, a_n1 = 0.f;
#pragma unroll
    for (int k = 0; k < KNBR; ++k) {
        a_i0 = fmaf(__uint_as_float(gi[k] << 16),         ie[k], a_i0);
        a_i1 = fmaf(__uint_as_float(gi[k] & 0xffff0000u), ie[k], a_i1);
        a_n0 = fmaf(__uint_as_float(gn[k] << 16),         ne[k], a_n0);
        a_n1 = fmaf(__uint_as_float(gn[k] & 0xffff0000u), ne[k], a_n1);
    }

    float ri = 1.f / (float)max(ci, 1);
    float rn = 1.f / (float)max(cn, 1);

    size_t o = (size_t)i * F + 2 * lane;
    float2 zv = *(const float2*)&z[o];
    float r0 = zv.x + a_i0 * ri + a_n0 * rn + bv[2 * lane];
    float r1 = zv.y + a_i1 * ri + a_n1 * rn + bv[2 * lane + 1];
    *(float2*)&z[o] = make_float2(fmaxf(r0, 0.f), fmaxf(r1, 0.f));
}

// ---------------------------------------------------------------------------
// Kernel C: passthrough outputs 1..5, written as float32 VALUES.
// ---------------------------------------------------------------------------
__global__ void pass_kernel(const int*   __restrict__ nh_idx,
                            const int*   __restrict__ int_idx,
                            const float* __restrict__ nh_e,
                            const float* __restrict__ int_e,
                            const int*   __restrict__ is_int,
                            float* __restrict__ out)
{
    const size_t NK    = (size_t)N_VERT * KNBR;
    const size_t total = 4 * NK + N_VERT;
    size_t t = (size_t)blockIdx.x * blockDim.x + threadIdx.x;
    if (t >= total) return;

    float v;
    if      (t <     NK) v = (float)nh_idx[t];
    else if (t < 2 * NK) v = (float)int_idx[t - NK];
    else if (t < 3 * NK) v = nh_e[t - 2 * NK];
    else if (t < 4 * NK) v = int_e[t - 3 * NK];
    else                 v = (float)is_int[t - 4 * NK];
    out[t] = v;
}

extern "C" void kernel_launch(void* const* d_in, const int* in_sizes, int n_in,
                              void* d_out, int out_size, void* d_ws, size_t ws_size,
                              hipStream_t stream) {
    const float* vert    = (const float*)d_in[0];
    const int*   nh_idx  = (const int*)  d_in[1];
    const int*   int_idx = (const int*)  d_in[2];
    const float* nh_e    = (const float*)d_in[3];
    const float* int_e   = (const float*)d_in[4];
    const int*   is_int  = (const int*)  d_in[5];
    const float* Wc      = (const float*)d_in[6];
    const float* Wi      = (const float*)d_in[7];
    const float* Wn      = (const float*)d_in[8];
    const float* bv      = (const float*)d_in[9];

    float* z        = (float*)d_out;                    // [N, F]
    float* out_rest = z + (size_t)N_VERT * F;           // passthrough chunks
    ushort16* pi    = (ushort16*)d_ws;                  // bf16 [N, F]
    ushort16* pn    = pi + (size_t)N_VERT * F;          // bf16 [N, F]
    ushort16* Wt    = pn + (size_t)N_VERT * F;          // bf16 [3][128][128]

    wconv_kernel<<<(3 * F * F + 255) / 256, 256, 0, stream>>>(Wc, Wi, Wn, Wt);
    mfma_proj_kernel<<<(N_VERT + 63) / 64, 256, 0, stream>>>(vert, Wt, z, pi, pn);
    agg_kernel<<<N_VERT / 4, 256, 0, stream>>>(
        (const uint32*)pi, (const uint32*)pn,
        (const int4*)int_idx, (const int4*)nh_idx,
        (const float4*)int_e, (const float4*)nh_e, bv, z);

    const size_t total = (size_t)4 * N_VERT * KNBR + N_VERT;
    pass_kernel<<<(int)((total + 255) / 256), 256, 0, stream>>>(
        nh_idx, int_idx, nh_e, int_e, is_int, out_rest);
}

// Round 5
// 146.307 us; speedup vs baseline: 2.0159x; 1.0259x over previous
//
#include <hip/hip_runtime.h>

#define N_VERT 50000
#define KNBR 20
#define F 128

typedef unsigned int uint32;
typedef unsigned short ushort16;
typedef __attribute__((ext_vector_type(8))) short bf16x8;
typedef __attribute__((ext_vector_type(4))) float f32x4;

__device__ __forceinline__ ushort16 f2bf(float x) {
    uint32 u = __float_as_uint(x);
    u += 0x7fff + ((u >> 16) & 1);        // round-to-nearest-even
    return (ushort16)(u >> 16);
}

// ---------------------------------------------------------------------------
// Kernel W: transpose+convert the three 128x128 weights to bf16, n-major.
// ---------------------------------------------------------------------------
__global__ __launch_bounds__(256) void wconv_kernel(
    const float* __restrict__ Wc, const float* __restrict__ Wi,
    const float* __restrict__ Wn, ushort16* __restrict__ Wt)
{
    int t = blockIdx.x * 256 + threadIdx.x;
    if (t >= 3 * F * F) return;
    int w = t >> 14;
    int r = t & 16383;
    int n = r & 127;
    int k = r >> 7;
    const float* W = (w == 0) ? Wc : ((w == 1) ? Wi : Wn);
    Wt[w * F * F + n * F + k] = f2bf(W[k * F + n]);
}

// ---------------------------------------------------------------------------
// Kernel A: three projections via bf16 MFMA (16x16x32).  (unchanged R4)
// ---------------------------------------------------------------------------
__global__ __launch_bounds__(256) void mfma_proj_kernel(
    const float*    __restrict__ vert,
    const ushort16* __restrict__ Wt,
    float*    __restrict__ zc,
    ushort16* __restrict__ pi,
    ushort16* __restrict__ pn)
{
    const int wave = threadIdx.x >> 6;
    const int lane = threadIdx.x & 63;
    const int lr   = lane & 15;
    const int lk   = lane >> 4;
    const int r0   = blockIdx.x * 64 + wave * 16;

    int rowA = r0 + lr; if (rowA > N_VERT - 1) rowA = N_VERT - 1;
    const float* vrow = vert + (size_t)rowA * F;
    bf16x8 afrag[4];
#pragma unroll
    for (int kk = 0; kk < 4; ++kk) {
        const float* p = vrow + kk * 32 + lk * 8;
        f32x4 lo = *(const f32x4*)p;
        f32x4 hi = *(const f32x4*)(p + 4);
#pragma unroll
        for (int j = 0; j < 4; ++j) {
            afrag[kk][j]     = (short)f2bf(lo[j]);
            afrag[kk][4 + j] = (short)f2bf(hi[j]);
        }
    }

    f32x4 acc[3][8];
#pragma unroll
    for (int w = 0; w < 3; ++w)
#pragma unroll
        for (int nt = 0; nt < 8; ++nt) acc[w][nt] = (f32x4)(0.f);

#pragma unroll
    for (int kk = 0; kk < 4; ++kk) {
#pragma unroll
        for (int nt = 0; nt < 8; ++nt) {
            size_t boff = (size_t)(nt * 16 + lr) * F + kk * 32 + lk * 8;
#pragma unroll
            for (int w = 0; w < 3; ++w) {
                bf16x8 b = *(const bf16x8*)(Wt + w * F * F + boff);
                acc[w][nt] = __builtin_amdgcn_mfma_f32_16x16x32_bf16(
                    afrag[kk], b, acc[w][nt], 0, 0, 0);
            }
        }
    }

#pragma unroll
    for (int nt = 0; nt < 8; ++nt) {
#pragma unroll
        for (int j = 0; j < 4; ++j) {
            int row = r0 + lk * 4 + j;
            if (row < N_VERT) {
                size_t o = (size_t)row * F + nt * 16 + lr;
                zc[o] = acc[0][nt][j];
                pi[o] = f2bf(acc[1][nt][j]);
                pn[o] = f2bf(acc[2][nt][j]);
            }
        }
    }
}

// ---------------------------------------------------------------------------
// Kernel B: gather-aggregate, 4 vertices per wave via dwordx4 gathers.
// Lane = (vertex-group lane>>4, filter-group lane&15). One gather instr
// fetches 4 vertex rows x 256 B (16 B/lane). 4x fewer VMEM instructions
// and waves than the per-vertex-wave scheme; gathers batched 10-deep and
// unconditional (validity folded into masked edge weights).
// ---------------------------------------------------------------------------
__global__ __launch_bounds__(256) void agg_kernel(
    const uint4*  __restrict__ pi4,   // bf16 [N][128] viewed as [N][16] uint4
    const uint4*  __restrict__ pn4,
    const int4*   __restrict__ int_idx4,
    const int4*   __restrict__ nh_idx4,
    const float4* __restrict__ int_e4,
    const float4* __restrict__ nh_e4,
    const float*  __restrict__ bv,
    float* __restrict__ z)   // holds Zc on entry; overwritten with result
{
    const int lane = threadIdx.x & 63;
    const int wave = threadIdx.x >> 6;
    const int vg   = lane >> 4;
    const int fg   = lane & 15;
    const int i    = (blockIdx.x * 4 + wave) * 4 + vg;   // 3125*16 == N_VERT

    float2 ai[4], an[4];
#pragma unroll
    for (int j = 0; j < 4; ++j) { ai[j] = make_float2(0.f, 0.f); an[j] = make_float2(0.f, 0.f); }
    int ci = 0, cn = 0;

    // ---------------- interface edges ----------------
    {
        int sidx[KNBR]; float me[KNBR];
#pragma unroll
        for (int q = 0; q < 5; ++q) {
            int4   a = int_idx4[i * 5 + q];
            float4 e = int_e4[i * 5 + q];
            int   av[4] = {a.x, a.y, a.z, a.w};
            float ev[4] = {e.x, e.y, e.z, e.w};
#pragma unroll
            for (int j = 0; j < 4; ++j) {
                bool v = av[j] >= 0;
                ci += v;
                sidx[4 * q + j] = v ? av[j] : 0;
                me[4 * q + j]   = v ? ev[j] : 0.f;
            }
        }
#pragma unroll
        for (int b = 0; b < 2; ++b) {
            uint4 g[10];
#pragma unroll
            for (int t = 0; t < 10; ++t)
                g[t] = pi4[(size_t)sidx[b * 10 + t] * 16 + fg];
#pragma unroll
            for (int t = 0; t < 10; ++t) {
                float e = me[b * 10 + t];
                uint32 d[4] = {g[t].x, g[t].y, g[t].z, g[t].w};
#pragma unroll
                for (int j = 0; j < 4; ++j) {
                    ai[j].x = fmaf(__uint_as_float(d[j] << 16),         e, ai[j].x);
                    ai[j].y = fmaf(__uint_as_float(d[j] & 0xffff0000u), e, ai[j].y);
                }
            }
        }
    }
    // ---------------- neighborhood edges ----------------
    {
        int sidx[KNBR]; float me[KNBR];
#pragma unroll
        for (int q = 0; q < 5; ++q) {
            int4   a = nh_idx4[i * 5 + q];
            float4 e = nh_e4[i * 5 + q];
            int   av[4] = {a.x, a.y, a.z, a.w};
            float ev[4] = {e.x, e.y, e.z, e.w};
#pragma unroll
            for (int j = 0; j < 4; ++j) {
                bool v = av[j] >= 0;
                cn += v;
                sidx[4 * q + j] = v ? av[j] : 0;
                me[4 * q + j]   = v ? ev[j] : 0.f;
            }
        }
#pragma unroll
        for (int b = 0; b < 2; ++b) {
            uint4 g[10];
#pragma unroll
            for (int t = 0; t < 10; ++t)
                g[t] = pn4[(size_t)sidx[b * 10 + t] * 16 + fg];
#pragma unroll
            for (int t = 0; t < 10; ++t) {
                float e = me[b * 10 + t];
                uint32 d[4] = {g[t].x, g[t].y, g[t].z, g[t].w};
#pragma unroll
                for (int j = 0; j < 4; ++j) {
                    an[j].x = fmaf(__uint_as_float(d[j] << 16),         e, an[j].x);
                    an[j].y = fmaf(__uint_as_float(d[j] & 0xffff0000u), e, an[j].y);
                }
            }
        }
    }

    float ri = 1.f / (float)max(ci, 1);
    float rn = 1.f / (float)max(cn, 1);

    // filters fg*8 .. fg*8+7 of row i
    float* zp = z + (size_t)i * F + fg * 8;
    float4 z0 = *(const float4*)zp;
    float4 z1 = *(const float4*)(zp + 4);
    float4 b0 = *(const float4*)(bv + fg * 8);
    float4 b1 = *(const float4*)(bv + fg * 8 + 4);

    float4 r0, r1;
    r0.x = fmaxf(z0.x + ai[0].x * ri + an[0].x * rn + b0.x, 0.f);
    r0.y = fmaxf(z0.y + ai[0].y * ri + an[0].y * rn + b0.y, 0.f);
    r0.z = fmaxf(z0.z + ai[1].x * ri + an[1].x * rn + b0.z, 0.f);
    r0.w = fmaxf(z0.w + ai[1].y * ri + an[1].y * rn + b0.w, 0.f);
    r1.x = fmaxf(z1.x + ai[2].x * ri + an[2].x * rn + b1.x, 0.f);
    r1.y = fmaxf(z1.y + ai[2].y * ri + an[2].y * rn + b1.y, 0.f);
    r1.z = fmaxf(z1.z + ai[3].x * ri + an[3].x * rn + b1.z, 0.f);
    r1.w = fmaxf(z1.w + ai[3].y * ri + an[3].y * rn + b1.w, 0.f);
    *(float4*)zp       = r0;
    *(float4*)(zp + 4) = r1;
}

// ---------------------------------------------------------------------------
// Kernel C: passthrough outputs 1..5, written as float32 VALUES.
// ---------------------------------------------------------------------------
__global__ void pass_kernel(const int*   __restrict__ nh_idx,
                            const int*   __restrict__ int_idx,
                            const float* __restrict__ nh_e,
                            const float* __restrict__ int_e,
                            const int*   __restrict__ is_int,
                            float* __restrict__ out)
{
    const size_t NK    = (size_t)N_VERT * KNBR;
    const size_t total = 4 * NK + N_VERT;
    size_t t = (size_t)blockIdx.x * blockDim.x + threadIdx.x;
    if (t >= total) return;

    float v;
    if      (t <     NK) v = (float)nh_idx[t];
    else if (t < 2 * NK) v = (float)int_idx[t - NK];
    else if (t < 3 * NK) v = nh_e[t - 2 * NK];
    else if (t < 4 * NK) v = int_e[t - 3 * NK];
    else                 v = (float)is_int[t - 4 * NK];
    out[t] = v;
}

extern "C" void kernel_launch(void* const* d_in, const int* in_sizes, int n_in,
                              void* d_out, int out_size, void* d_ws, size_t ws_size,
                              hipStream_t stream) {
    const float* vert    = (const float*)d_in[0];
    const int*   nh_idx  = (const int*)  d_in[1];
    const int*   int_idx = (const int*)  d_in[2];
    const float* nh_e    = (const float*)d_in[3];
    const float* int_e   = (const float*)d_in[4];
    const int*   is_int  = (const int*)  d_in[5];
    const float* Wc      = (const float*)d_in[6];
    const float* Wi      = (const float*)d_in[7];
    const float* Wn      = (const float*)d_in[8];
    const float* bv      = (const float*)d_in[9];

    float* z        = (float*)d_out;                    // [N, F]
    float* out_rest = z + (size_t)N_VERT * F;           // passthrough chunks
    ushort16* pi    = (ushort16*)d_ws;                  // bf16 [N, F]
    ushort16* pn    = pi + (size_t)N_VERT * F;          // bf16 [N, F]
    ushort16* Wt    = pn + (size_t)N_VERT * F;          // bf16 [3][128][128]

    wconv_kernel<<<(3 * F * F + 255) / 256, 256, 0, stream>>>(Wc, Wi, Wn, Wt);
    mfma_proj_kernel<<<(N_VERT + 63) / 64, 256, 0, stream>>>(vert, Wt, z, pi, pn);
    agg_kernel<<<N_VERT / 16, 256, 0, stream>>>(
        (const uint4*)pi, (const uint4*)pn,
        (const int4*)int_idx, (const int4*)nh_idx,
        (const float4*)int_e, (const float4*)nh_e, bv, z);

    const size_t total = (size_t)4 * N_VERT * KNBR + N_VERT;
    pass_kernel<<<(int)((total + 255) / 256), 256, 0, stream>>>(
        nh_idx, int_idx, nh_e, int_e, is_int, out_rest);
}

// Round 6
// 121.435 us; speedup vs baseline: 2.4287x; 1.2048x over previous
//
#include <hip/hip_runtime.h>

#define N_VERT 50000
#define KNBR 20
#define F 128

typedef unsigned int uint32;
typedef unsigned short ushort16;
typedef __attribute__((ext_vector_type(8))) short bf16x8;
typedef __attribute__((ext_vector_type(4))) float f32x4;

__device__ __forceinline__ ushort16 f2bf(float x) {
    uint32 u = __float_as_uint(x);
    u += 0x7fff + ((u >> 16) & 1);        // round-to-nearest-even
    return (ushort16)(u >> 16);
}

// ---------------------------------------------------------------------------
// Kernel W: convert weights to bf16 in MFMA-FRAGMENT-LINEAR layout:
// Wt[((w*4+kk)*8+nt)*512 + lane*8 + e] = W_w[kk*32+(lane>>4)*8+e][nt*16+(lane&15)]
// so each B-fragment load in proj is one fully-coalesced 1KB wave request.
// ---------------------------------------------------------------------------
__global__ __launch_bounds__(256) void wconv_kernel(
    const float* __restrict__ Wc, const float* __restrict__ Wi,
    const float* __restrict__ Wn, ushort16* __restrict__ Wt)
{
    int t = blockIdx.x * 256 + threadIdx.x;
    if (t >= 3 * F * F) return;
    int w    = t >> 14;
    int r    = t & 16383;
    int kk   = r >> 12;
    int r2   = r & 4095;
    int nt   = r2 >> 9;
    int r3   = r2 & 511;
    int lane = r3 >> 3;
    int e    = r3 & 7;
    int k = kk * 32 + (lane >> 4) * 8 + e;
    int n = nt * 16 + (lane & 15);
    const float* W = (w == 0) ? Wc : ((w == 1) ? Wi : Wn);
    Wt[t] = f2bf(W[k * F + n]);
}

// ---------------------------------------------------------------------------
// Kernel A: three projections via bf16 MFMA (16x16x32).
// B loads: fragment-linear Wt -> 1KB coalesced per instr (was 16-line scatter).
// Stores: staged through padded LDS (stride 129 f32 / 136 u16, <=2-way banks)
// then written back coalesced 16B/lane (was 16-row scatter per instr).
// ---------------------------------------------------------------------------
__global__ __launch_bounds__(256) void mfma_proj_kernel(
    const float*    __restrict__ vert,
    const ushort16* __restrict__ Wt,     // fragment-linear [3][4][8][64][8]
    float*    __restrict__ zc,
    ushort16* __restrict__ pi,
    ushort16* __restrict__ pn)
{
    __shared__ float          zs_all[4][16 * 129];   // 33 KB
    __shared__ unsigned short ps_all[4][16 * 136];   // 17 KB

    const int wave = threadIdx.x >> 6;
    const int lane = threadIdx.x & 63;
    const int lr   = lane & 15;
    const int lk   = lane >> 4;
    const int rb   = blockIdx.x * 64 + wave * 16;

    // A fragments (V rows read once, converted inline)
    int rowA = rb + lr; if (rowA > N_VERT - 1) rowA = N_VERT - 1;
    const float* vrow = vert + (size_t)rowA * F;
    bf16x8 afrag[4];
#pragma unroll
    for (int kk = 0; kk < 4; ++kk) {
        const float* p = vrow + kk * 32 + lk * 8;
        f32x4 lo = *(const f32x4*)p;
        f32x4 hi = *(const f32x4*)(p + 4);
#pragma unroll
        for (int j = 0; j < 4; ++j) {
            afrag[kk][j]     = (short)f2bf(lo[j]);
            afrag[kk][4 + j] = (short)f2bf(hi[j]);
        }
    }

    f32x4 acc[3][8];
#pragma unroll
    for (int w = 0; w < 3; ++w)
#pragma unroll
        for (int nt = 0; nt < 8; ++nt) acc[w][nt] = (f32x4)(0.f);

#pragma unroll
    for (int kk = 0; kk < 4; ++kk) {
#pragma unroll
        for (int nt = 0; nt < 8; ++nt) {
#pragma unroll
            for (int w = 0; w < 3; ++w) {
                bf16x8 b = *(const bf16x8*)(
                    Wt + ((size_t)((w * 4 + kk) * 8 + nt)) * 512 + lane * 8);
                acc[w][nt] = __builtin_amdgcn_mfma_f32_16x16x32_bf16(
                    afrag[kk], b, acc[w][nt], 0, 0, 0);
            }
        }
    }

    // ---- zc: stage to LDS, store coalesced (8 instrs x 2 rows) ----
    float* zs = zs_all[wave];
#pragma unroll
    for (int nt = 0; nt < 8; ++nt)
#pragma unroll
        for (int j = 0; j < 4; ++j)
            zs[(lk * 4 + j) * 129 + nt * 16 + lr] = acc[0][nt][j];
#pragma unroll
    for (int i = 0; i < 8; ++i) {
        int r2  = 2 * i + (lane >> 5);
        int col = (lane & 31) * 4;
        f32x4 v = *(const f32x4*)&zs[r2 * 129 + col];
        int row = rb + r2;
        if (row < N_VERT) *(f32x4*)(zc + (size_t)row * F + col) = v;
    }

    // ---- pi: stage bf16 to LDS, store coalesced (4 instrs x 4 rows) ----
    unsigned short* ps = ps_all[wave];
#pragma unroll
    for (int nt = 0; nt < 8; ++nt)
#pragma unroll
        for (int j = 0; j < 4; ++j)
            ps[(lk * 4 + j) * 136 + nt * 16 + lr] = f2bf(acc[1][nt][j]);
#pragma unroll
    for (int i = 0; i < 4; ++i) {
        int r4  = 4 * i + (lane >> 4);
        int col = (lane & 15) * 8;
        uint4 v = *(const uint4*)&ps[r4 * 136 + col];
        int row = rb + r4;
        if (row < N_VERT) *(uint4*)(pi + (size_t)row * F + col) = v;
    }

    // ---- pn: reuse ps buffer ----
#pragma unroll
    for (int nt = 0; nt < 8; ++nt)
#pragma unroll
        for (int j = 0; j < 4; ++j)
            ps[(lk * 4 + j) * 136 + nt * 16 + lr] = f2bf(acc[2][nt][j]);
#pragma unroll
    for (int i = 0; i < 4; ++i) {
        int r4  = 4 * i + (lane >> 4);
        int col = (lane & 15) * 8;
        uint4 v = *(const uint4*)&ps[r4 * 136 + col];
        int row = rb + r4;
        if (row < N_VERT) *(uint4*)(pn + (size_t)row * F + col) = v;
    }
}

// ---------------------------------------------------------------------------
// Kernel B: gather-aggregate, 4 vertices/wave via dwordx4 gathers, now with
// ALL 20 gathers of an edge-type in flight (launch_bounds(256,2) frees VGPRs
// -- R5's VGPR=56 shows the compiler had serialized the 10-deep batches).
// ---------------------------------------------------------------------------
__global__ __launch_bounds__(256, 2) void agg_kernel(
    const uint4*  __restrict__ pi4,
    const uint4*  __restrict__ pn4,
    const int4*   __restrict__ int_idx4,
    const int4*   __restrict__ nh_idx4,
    const float4* __restrict__ int_e4,
    const float4* __restrict__ nh_e4,
    const float*  __restrict__ bv,
    float* __restrict__ z)
{
    const int lane = threadIdx.x & 63;
    const int wave = threadIdx.x >> 6;
    const int vg   = lane >> 4;
    const int fg   = lane & 15;
    const int i    = (blockIdx.x * 4 + wave) * 4 + vg;

    float2 ai[4], an[4];
#pragma unroll
    for (int j = 0; j < 4; ++j) { ai[j] = make_float2(0.f, 0.f); an[j] = make_float2(0.f, 0.f); }
    int ci = 0, cn = 0;

    // ---------------- interface edges ----------------
    {
        int sidx[KNBR]; float me[KNBR];
#pragma unroll
        for (int q = 0; q < 5; ++q) {
            int4   a = int_idx4[i * 5 + q];
            float4 e = int_e4[i * 5 + q];
            int   av[4] = {a.x, a.y, a.z, a.w};
            float ev[4] = {e.x, e.y, e.z, e.w};
#pragma unroll
            for (int j = 0; j < 4; ++j) {
                bool v = av[j] >= 0;
                ci += v;
                sidx[4 * q + j] = v ? av[j] : 0;
                me[4 * q + j]   = v ? ev[j] : 0.f;
            }
        }
        uint4 g[KNBR];
#pragma unroll
        for (int t = 0; t < KNBR; ++t)
            g[t] = pi4[(size_t)sidx[t] * 16 + fg];
#pragma unroll
        for (int t = 0; t < KNBR; ++t) {
            float e = me[t];
            uint32 d[4] = {g[t].x, g[t].y, g[t].z, g[t].w};
#pragma unroll
            for (int j = 0; j < 4; ++j) {
                ai[j].x = fmaf(__uint_as_float(d[j] << 16),         e, ai[j].x);
                ai[j].y = fmaf(__uint_as_float(d[j] & 0xffff0000u), e, ai[j].y);
            }
        }
    }
    // ---------------- neighborhood edges ----------------
    {
        int sidx[KNBR]; float me[KNBR];
#pragma unroll
        for (int q = 0; q < 5; ++q) {
            int4   a = nh_idx4[i * 5 + q];
            float4 e = nh_e4[i * 5 + q];
            int   av[4] = {a.x, a.y, a.z, a.w};
            float ev[4] = {e.x, e.y, e.z, e.w};
#pragma unroll
            for (int j = 0; j < 4; ++j) {
                bool v = av[j] >= 0;
                cn += v;
                sidx[4 * q + j] = v ? av[j] : 0;
                me[4 * q + j]   = v ? ev[j] : 0.f;
            }
        }
        uint4 g[KNBR];
#pragma unroll
        for (int t = 0; t < KNBR; ++t)
            g[t] = pn4[(size_t)sidx[t] * 16 + fg];
#pragma unroll
        for (int t = 0; t < KNBR; ++t) {
            float e = me[t];
            uint32 d[4] = {g[t].x, g[t].y, g[t].z, g[t].w};
#pragma unroll
            for (int j = 0; j < 4; ++j) {
                an[j].x = fmaf(__uint_as_float(d[j] << 16),         e, an[j].x);
                an[j].y = fmaf(__uint_as_float(d[j] & 0xffff0000u), e, an[j].y);
            }
        }
    }

    float ri = 1.f / (float)max(ci, 1);
    float rn = 1.f / (float)max(cn, 1);

    float* zp = z + (size_t)i * F + fg * 8;
    float4 z0 = *(const float4*)zp;
    float4 z1 = *(const float4*)(zp + 4);
    float4 b0 = *(const float4*)(bv + fg * 8);
    float4 b1 = *(const float4*)(bv + fg * 8 + 4);

    float4 r0, r1;
    r0.x = fmaxf(z0.x + ai[0].x * ri + an[0].x * rn + b0.x, 0.f);
    r0.y = fmaxf(z0.y + ai[0].y * ri + an[0].y * rn + b0.y, 0.f);
    r0.z = fmaxf(z0.z + ai[1].x * ri + an[1].x * rn + b0.z, 0.f);
    r0.w = fmaxf(z0.w + ai[1].y * ri + an[1].y * rn + b0.w, 0.f);
    r1.x = fmaxf(z1.x + ai[2].x * ri + an[2].x * rn + b1.x, 0.f);
    r1.y = fmaxf(z1.y + ai[2].y * ri + an[2].y * rn + b1.y, 0.f);
    r1.z = fmaxf(z1.z + ai[3].x * ri + an[3].x * rn + b1.z, 0.f);
    r1.w = fmaxf(z1.w + ai[3].y * ri + an[3].y * rn + b1.w, 0.f);
    *(float4*)zp       = r0;
    *(float4*)(zp + 4) = r1;
}

// ---------------------------------------------------------------------------
// Kernel C: passthrough outputs 1..5, written as float32 VALUES.
// ---------------------------------------------------------------------------
__global__ void pass_kernel(const int*   __restrict__ nh_idx,
                            const int*   __restrict__ int_idx,
                            const float* __restrict__ nh_e,
                            const float* __restrict__ int_e,
                            const int*   __restrict__ is_int,
                            float* __restrict__ out)
{
    const size_t NK    = (size_t)N_VERT * KNBR;
    const size_t total = 4 * NK + N_VERT;
    size_t t = (size_t)blockIdx.x * blockDim.x + threadIdx.x;
    if (t >= total) return;

    float v;
    if      (t <     NK) v = (float)nh_idx[t];
    else if (t < 2 * NK) v = (float)int_idx[t - NK];
    else if (t < 3 * NK) v = nh_e[t - 2 * NK];
    else if (t < 4 * NK) v = int_e[t - 3 * NK];
    else                 v = (float)is_int[t - 4 * NK];
    out[t] = v;
}

extern "C" void kernel_launch(void* const* d_in, const int* in_sizes, int n_in,
                              void* d_out, int out_size, void* d_ws, size_t ws_size,
                              hipStream_t stream) {
    const float* vert    = (const float*)d_in[0];
    const int*   nh_idx  = (const int*)  d_in[1];
    const int*   int_idx = (const int*)  d_in[2];
    const float* nh_e    = (const float*)d_in[3];
    const float* int_e   = (const float*)d_in[4];
    const int*   is_int  = (const int*)  d_in[5];
    const float* Wc      = (const float*)d_in[6];
    const float* Wi      = (const float*)d_in[7];
    const float* Wn      = (const float*)d_in[8];
    const float* bv      = (const float*)d_in[9];

    float* z        = (float*)d_out;                    // [N, F]
    float* out_rest = z + (size_t)N_VERT * F;           // passthrough chunks
    ushort16* pi    = (ushort16*)d_ws;                  // bf16 [N, F]
    ushort16* pn    = pi + (size_t)N_VERT * F;          // bf16 [N, F]
    ushort16* Wt    = pn + (size_t)N_VERT * F;          // bf16 fragment-linear

    wconv_kernel<<<(3 * F * F + 255) / 256, 256, 0, stream>>>(Wc, Wi, Wn, Wt);
    mfma_proj_kernel<<<(N_VERT + 63) / 64, 256, 0, stream>>>(vert, Wt, z, pi, pn);
    agg_kernel<<<N_VERT / 16, 256, 0, stream>>>(
        (const uint4*)pi, (const uint4*)pn,
        (const int4*)int_idx, (const int4*)nh_idx,
        (const float4*)int_e, (const float4*)nh_e, bv, z);

    const size_t total = (size_t)4 * N_VERT * KNBR + N_VERT;
    pass_kernel<<<(int)((total + 255) / 256), 256, 0, stream>>>(
        nh_idx, int_idx, nh_e, int_e, is_int, out_rest);
}

// Round 7
// 97.921 us; speedup vs baseline: 3.0120x; 1.2401x over previous
//
#include <hip/hip_runtime.h>

#define N_VERT 50000
#define KNBR 20
#define F 128

typedef unsigned int uint32;
typedef unsigned short ushort16;
typedef unsigned char uint8;
typedef __attribute__((ext_vector_type(8))) short bf16x8;
typedef __attribute__((ext_vector_type(4))) float f32x4;

__device__ __forceinline__ ushort16 f2bf(float x) {
    uint32 u = __float_as_uint(x);
    u += 0x7fff + ((u >> 16) & 1);        // round-to-nearest-even
    return (ushort16)(u >> 16);
}

// ---------------------------------------------------------------------------
// Kernel W: weights -> bf16, MFMA-fragment-linear layout (unchanged R6).
// ---------------------------------------------------------------------------
__global__ __launch_bounds__(256) void wconv_kernel(
    const float* __restrict__ Wc, const float* __restrict__ Wi,
    const float* __restrict__ Wn, ushort16* __restrict__ Wt)
{
    int t = blockIdx.x * 256 + threadIdx.x;
    if (t >= 3 * F * F) return;
    int w    = t >> 14;
    int r    = t & 16383;
    int kk   = r >> 12;
    int r2   = r & 4095;
    int nt   = r2 >> 9;
    int r3   = r2 & 511;
    int lane = r3 >> 3;
    int e    = r3 & 7;
    int k = kk * 32 + (lane >> 4) * 8 + e;
    int n = nt * 16 + (lane & 15);
    const float* W = (w == 0) ? Wc : ((w == 1) ? Wi : Wn);
    Wt[t] = f2bf(W[k * F + n]);
}

// Quantize one wave's 16x128 accumulator tile to int8 + per-row scale.
// Stages f32 via LDS (per-wave private, stride 129), reduces row absmax in
// 4-lane groups, packs 32 int8/lane, stores 2x uint4 coalesced.
__device__ __forceinline__ void quant_store(
    const f32x4 (&a)[8], float* zs, int lane, int rb,
    uint8* __restrict__ pay, float* __restrict__ scaleArr)
{
    const int lr = lane & 15, lk = lane >> 4;
#pragma unroll
    for (int nt = 0; nt < 8; ++nt)
#pragma unroll
        for (int j = 0; j < 4; ++j)
            zs[(lk * 4 + j) * 129 + nt * 16 + lr] = a[nt][j];

    int row = lane >> 2;           // 0..15
    int seg = (lane & 3) * 32;     // col base
    const float* src = zs + row * 129 + seg;
    float v[32];
    float m = 0.f;
#pragma unroll
    for (int t = 0; t < 8; ++t) {
        f32x4 x = *(const f32x4*)(src + 4 * t);
#pragma unroll
        for (int j = 0; j < 4; ++j) {
            v[4 * t + j] = x[j];
            m = fmaxf(m, fabsf(x[j]));
        }
    }
    m = fmaxf(m, __shfl_xor(m, 1));
    m = fmaxf(m, __shfl_xor(m, 2));
    float scale = m * (1.f / 127.f);
    float inv   = (m > 0.f) ? 127.f / m : 0.f;

    uint32 pk[8];
#pragma unroll
    for (int t = 0; t < 8; ++t) {
        uint32 p = 0;
#pragma unroll
        for (int j = 0; j < 4; ++j) {
            int qi = (int)rintf(v[4 * t + j] * inv);
            p |= ((uint32)(qi & 255)) << (8 * j);
        }
        pk[t] = p;
    }
    int grow = rb + row;
    if (grow < N_VERT) {
        uint4* dst = (uint4*)(pay + (size_t)grow * 128 + seg);
        dst[0] = make_uint4(pk[0], pk[1], pk[2], pk[3]);
        dst[1] = make_uint4(pk[4], pk[5], pk[6], pk[7]);
        if ((lane & 3) == 0) scaleArr[grow] = scale;
    }
}

// ---------------------------------------------------------------------------
// Kernel A: three projections via bf16 MFMA. Zc stays f32; Pint/Pnh are
// quantized to int8 + per-row scale (halves agg's gather payload).
// ---------------------------------------------------------------------------
__global__ __launch_bounds__(256) void mfma_proj_kernel(
    const float*    __restrict__ vert,
    const ushort16* __restrict__ Wt,     // fragment-linear [3][4][8][64][8]
    float* __restrict__ zc,
    uint8* __restrict__ pay_i, float* __restrict__ sc_i,
    uint8* __restrict__ pay_n, float* __restrict__ sc_n)
{
    __shared__ float zs_all[4][16 * 129];   // 33 KB, per-wave private

    const int wave = threadIdx.x >> 6;
    const int lane = threadIdx.x & 63;
    const int lr   = lane & 15;
    const int lk   = lane >> 4;
    const int rb   = blockIdx.x * 64 + wave * 16;

    int rowA = rb + lr; if (rowA > N_VERT - 1) rowA = N_VERT - 1;
    const float* vrow = vert + (size_t)rowA * F;
    bf16x8 afrag[4];
#pragma unroll
    for (int kk = 0; kk < 4; ++kk) {
        const float* p = vrow + kk * 32 + lk * 8;
        f32x4 lo = *(const f32x4*)p;
        f32x4 hi = *(const f32x4*)(p + 4);
#pragma unroll
        for (int j = 0; j < 4; ++j) {
            afrag[kk][j]     = (short)f2bf(lo[j]);
            afrag[kk][4 + j] = (short)f2bf(hi[j]);
        }
    }

    f32x4 acc[3][8];
#pragma unroll
    for (int w = 0; w < 3; ++w)
#pragma unroll
        for (int nt = 0; nt < 8; ++nt) acc[w][nt] = (f32x4)(0.f);

#pragma unroll
    for (int kk = 0; kk < 4; ++kk) {
#pragma unroll
        for (int nt = 0; nt < 8; ++nt) {
#pragma unroll
            for (int w = 0; w < 3; ++w) {
                bf16x8 b = *(const bf16x8*)(
                    Wt + ((size_t)((w * 4 + kk) * 8 + nt)) * 512 + lane * 8);
                acc[w][nt] = __builtin_amdgcn_mfma_f32_16x16x32_bf16(
                    afrag[kk], b, acc[w][nt], 0, 0, 0);
            }
        }
    }

    // ---- zc: stage to LDS, store coalesced ----
    float* zs = zs_all[wave];
#pragma unroll
    for (int nt = 0; nt < 8; ++nt)
#pragma unroll
        for (int j = 0; j < 4; ++j)
            zs[(lk * 4 + j) * 129 + nt * 16 + lr] = acc[0][nt][j];
#pragma unroll
    for (int i = 0; i < 8; ++i) {
        int r2  = 2 * i + (lane >> 5);
        int col = (lane & 31) * 4;
        f32x4 v = *(const f32x4*)&zs[r2 * 129 + col];
        int row = rb + r2;
        if (row < N_VERT) *(f32x4*)(zc + (size_t)row * F + col) = v;
    }

    // ---- pi / pn: int8 + row scale ----
    quant_store(acc[1], zs, lane, rb, pay_i, sc_i);
    quant_store(acc[2], zs, lane, rb, pay_n, sc_n);
}

// ---------------------------------------------------------------------------
// Kernel B: gather-aggregate on int8 row-scaled payload.
// 4 vertices/wave; lane = (vg=lane>>4, fg=lane&15); uint2 gather = 8 int8
// = filters fg*8..fg*8+7 of one row (128 B/row -> 2 lines, 8 lines/instr).
// Per-row scale folded into the edge weight before unpacking.
// ---------------------------------------------------------------------------
__global__ __launch_bounds__(256) void agg_kernel(
    const uint8*  __restrict__ pay_i, const float* __restrict__ sc_i,
    const uint8*  __restrict__ pay_n, const float* __restrict__ sc_n,
    const int4*   __restrict__ int_idx4,
    const int4*   __restrict__ nh_idx4,
    const float4* __restrict__ int_e4,
    const float4* __restrict__ nh_e4,
    const float*  __restrict__ bv,
    float* __restrict__ z)
{
    const int lane = threadIdx.x & 63;
    const int wave = threadIdx.x >> 6;
    const int vg   = lane >> 4;
    const int fg   = lane & 15;
    const int i    = (blockIdx.x * 4 + wave) * 4 + vg;

    float a_i[8], a_n[8];
#pragma unroll
    for (int j = 0; j < 8; ++j) { a_i[j] = 0.f; a_n[j] = 0.f; }
    int ci = 0, cn = 0;

    // ---------------- interface edges ----------------
    {
        int sidx[KNBR]; float f[KNBR];
#pragma unroll
        for (int q = 0; q < 5; ++q) {
            int4   a = int_idx4[i * 5 + q];
            float4 e = int_e4[i * 5 + q];
            int   av[4] = {a.x, a.y, a.z, a.w};
            float ev[4] = {e.x, e.y, e.z, e.w};
#pragma unroll
            for (int j = 0; j < 4; ++j) {
                bool v = av[j] >= 0;
                ci += v;
                sidx[4 * q + j] = v ? av[j] : 0;
                f[4 * q + j]    = v ? ev[j] : 0.f;
            }
        }
#pragma unroll
        for (int k = 0; k < KNBR; ++k) f[k] *= sc_i[sidx[k]];
        uint2 g[KNBR];
#pragma unroll
        for (int k = 0; k < KNBR; ++k)
            g[k] = *(const uint2*)(pay_i + (size_t)sidx[k] * 128 + fg * 8);
#pragma unroll
        for (int k = 0; k < KNBR; ++k) {
            float e = f[k];
            uint32 d0 = g[k].x, d1 = g[k].y;
#pragma unroll
            for (int b = 0; b < 4; ++b) {
                a_i[b]     = fmaf((float)((int)(d0 << (24 - 8 * b)) >> 24), e, a_i[b]);
                a_i[4 + b] = fmaf((float)((int)(d1 << (24 - 8 * b)) >> 24), e, a_i[4 + b]);
            }
        }
    }
    // ---------------- neighborhood edges ----------------
    {
        int sidx[KNBR]; float f[KNBR];
#pragma unroll
        for (int q = 0; q < 5; ++q) {
            int4   a = nh_idx4[i * 5 + q];
            float4 e = nh_e4[i * 5 + q];
            int   av[4] = {a.x, a.y, a.z, a.w};
            float ev[4] = {e.x, e.y, e.z, e.w};
#pragma unroll
            for (int j = 0; j < 4; ++j) {
                bool v = av[j] >= 0;
                cn += v;
                sidx[4 * q + j] = v ? av[j] : 0;
                f[4 * q + j]    = v ? ev[j] : 0.f;
            }
        }
#pragma unroll
        for (int k = 0; k < KNBR; ++k) f[k] *= sc_n[sidx[k]];
        uint2 g[KNBR];
#pragma unroll
        for (int k = 0; k < KNBR; ++k)
            g[k] = *(const uint2*)(pay_n + (size_t)sidx[k] * 128 + fg * 8);
#pragma unroll
        for (int k = 0; k < KNBR; ++k) {
            float e = f[k];
            uint32 d0 = g[k].x, d1 = g[k].y;
#pragma unroll
            for (int b = 0; b < 4; ++b) {
                a_n[b]     = fmaf((float)((int)(d0 << (24 - 8 * b)) >> 24), e, a_n[b]);
                a_n[4 + b] = fmaf((float)((int)(d1 << (24 - 8 * b)) >> 24), e, a_n[4 + b]);
            }
        }
    }

    float ri = 1.f / (float)max(ci, 1);
    float rn = 1.f / (float)max(cn, 1);

    float* zp = z + (size_t)i * F + fg * 8;
    float4 z0 = *(const float4*)zp;
    float4 z1 = *(const float4*)(zp + 4);
    float4 b0 = *(const float4*)(bv + fg * 8);
    float4 b1 = *(const float4*)(bv + fg * 8 + 4);

    float4 r0, r1;
    r0.x = fmaxf(z0.x + a_i[0] * ri + a_n[0] * rn + b0.x, 0.f);
    r0.y = fmaxf(z0.y + a_i[1] * ri + a_n[1] * rn + b0.y, 0.f);
    r0.z = fmaxf(z0.z + a_i[2] * ri + a_n[2] * rn + b0.z, 0.f);
    r0.w = fmaxf(z0.w + a_i[3] * ri + a_n[3] * rn + b0.w, 0.f);
    r1.x = fmaxf(z1.x + a_i[4] * ri + a_n[4] * rn + b1.x, 0.f);
    r1.y = fmaxf(z1.y + a_i[5] * ri + a_n[5] * rn + b1.y, 0.f);
    r1.z = fmaxf(z1.z + a_i[6] * ri + a_n[6] * rn + b1.z, 0.f);
    r1.w = fmaxf(z1.w + a_i[7] * ri + a_n[7] * rn + b1.w, 0.f);
    *(float4*)zp       = r0;
    *(float4*)(zp + 4) = r1;
}

// ---------------------------------------------------------------------------
// Kernel C: passthrough outputs 1..5, written as float32 VALUES.
// ---------------------------------------------------------------------------
__global__ void pass_kernel(const int*   __restrict__ nh_idx,
                            const int*   __restrict__ int_idx,
                            const float* __restrict__ nh_e,
                            const float* __restrict__ int_e,
                            const int*   __restrict__ is_int,
                            float* __restrict__ out)
{
    const size_t NK    = (size_t)N_VERT * KNBR;
    const size_t total = 4 * NK + N_VERT;
    size_t t = (size_t)blockIdx.x * blockDim.x + threadIdx.x;
    if (t >= total) return;

    float v;
    if      (t <     NK) v = (float)nh_idx[t];
    else if (t < 2 * NK) v = (float)int_idx[t - NK];
    else if (t < 3 * NK) v = nh_e[t - 2 * NK];
    else if (t < 4 * NK) v = int_e[t - 3 * NK];
    else                 v = (float)is_int[t - 4 * NK];
    out[t] = v;
}

extern "C" void kernel_launch(void* const* d_in, const int* in_sizes, int n_in,
                              void* d_out, int out_size, void* d_ws, size_t ws_size,
                              hipStream_t stream) {
    const float* vert    = (const float*)d_in[0];
    const int*   nh_idx  = (const int*)  d_in[1];
    const int*   int_idx = (const int*)  d_in[2];
    const float* nh_e    = (const float*)d_in[3];
    const float* int_e   = (const float*)d_in[4];
    const int*   is_int  = (const int*)  d_in[5];
    const float* Wc      = (const float*)d_in[6];
    const float* Wi      = (const float*)d_in[7];
    const float* Wn      = (const float*)d_in[8];
    const float* bv      = (const float*)d_in[9];

    float* z        = (float*)d_out;                    // [N, F]
    float* out_rest = z + (size_t)N_VERT * F;           // passthrough chunks

    uint8* pay_i = (uint8*)d_ws;                        // int8 [N][128]
    uint8* pay_n = pay_i + (size_t)N_VERT * F;          // int8 [N][128]
    float* sc_i  = (float*)(pay_n + (size_t)N_VERT * F);// f32 [N]
    float* sc_n  = sc_i + N_VERT;                       // f32 [N]
    ushort16* Wt = (ushort16*)(sc_n + N_VERT);          // bf16 fragment-linear

    wconv_kernel<<<(3 * F * F + 255) / 256, 256, 0, stream>>>(Wc, Wi, Wn, Wt);
    mfma_proj_kernel<<<(N_VERT + 63) / 64, 256, 0, stream>>>(
        vert, Wt, z, pay_i, sc_i, pay_n, sc_n);
    agg_kernel<<<N_VERT / 16, 256, 0, stream>>>(
        pay_i, sc_i, pay_n, sc_n,
        (const int4*)int_idx, (const int4*)nh_idx,
        (const float4*)int_e, (const float4*)nh_e, bv, z);

    const size_t total = (size_t)4 * N_VERT * KNBR + N_VERT;
    pass_kernel<<<(int)((total + 255) / 256), 256, 0, stream>>>(
        nh_idx, int_idx, nh_e, int_e, is_int, out_rest);
}